// Round 2
// baseline (1130.389 us; speedup 1.0000x reference)
//
#include <hip/hip_runtime.h>
#include <hip/hip_bf16.h>
#include <stdint.h>

#define T_TOK 16384
#define HDIM  1024
#define FDIM  4096
#define NE    8
#define CAP   2560   // ceil(1.25 * 16384 / 8)

typedef __attribute__((ext_vector_type(8))) __bf16 bf16x8;
typedef __attribute__((ext_vector_type(4))) float  f32x4;

__device__ __forceinline__ unsigned short f2bf(float f) {
  union { float f; unsigned u; } c; c.f = f;
  unsigned u = c.u;
  return (unsigned short)((u + 0x7FFFu + ((u >> 16) & 1u)) >> 16);
}

__device__ __forceinline__ void gload_lds16(const void* g, void* lds) {
  __builtin_amdgcn_global_load_lds((const __attribute__((address_space(1))) void*)g,
                                   (__attribute__((address_space(3))) void*)lds,
                                   16, 0, 0);
}

// ---------------- transpose + fp32->bf16 convert: in (E,R,Cc) f32 -> out (E,Cc,R) bf16
__global__ __launch_bounds__(256)
void transpose_cvt(const float* __restrict__ in, unsigned short* __restrict__ out,
                   int R, int Cc) {
  __shared__ unsigned short tile[64][68];
  int e  = blockIdx.z;
  int rb = blockIdx.y << 6, cb = blockIdx.x << 6;
  const float* inp = in + (size_t)e * R * Cc;
  unsigned short* op = out + (size_t)e * R * Cc;
  int lc  = threadIdx.x & 63;
  int lr0 = threadIdx.x >> 6;
#pragma unroll
  for (int rr = 0; rr < 64; rr += 4) {
    int r = rr + lr0;
    float v = inp[(size_t)(rb + r) * Cc + cb + lc];
    tile[lc][r] = f2bf(v);
  }
  __syncthreads();
  int c0 = threadIdx.x >> 3;
  int h0 = (threadIdx.x & 7) << 3;
#pragma unroll
  for (int cc = 0; cc < 64; cc += 32) {
    int c = cc + c0;
    uint2 v0 = *(const uint2*)&tile[c][h0];
    uint2 v1 = *(const uint2*)&tile[c][h0 + 4];
    uint4 v; v.x = v0.x; v.y = v0.y; v.z = v1.x; v.w = v1.y;
    *(uint4*)(op + (size_t)(cb + c) * R + rb + h0) = v;
  }
}

// ---------------- transpose gate/up into interleaved wgu: rows (grp*64 + 0..31)=gate, (+32..63)=up
__global__ __launch_bounds__(256)
void transpose_cvt_gu(const float* __restrict__ in, unsigned short* __restrict__ out, int up) {
  __shared__ unsigned short tile[64][68];
  int e  = blockIdx.z;
  int rb = blockIdx.y << 6, cb = blockIdx.x << 6;   // rb over HDIM rows, cb over FDIM cols
  const float* inp = in + (size_t)e * HDIM * FDIM;
  unsigned short* op = out + (size_t)e * 2 * FDIM * HDIM;
  int lc  = threadIdx.x & 63;
  int lr0 = threadIdx.x >> 6;
#pragma unroll
  for (int rr = 0; rr < 64; rr += 4) {
    int r = rr + lr0;
    float v = inp[(size_t)(rb + r) * FDIM + cb + lc];
    tile[lc][r] = f2bf(v);
  }
  __syncthreads();
  int c0 = threadIdx.x >> 3;
  int h0 = (threadIdx.x & 7) << 3;
#pragma unroll
  for (int cc = 0; cc < 64; cc += 32) {
    int c = cc + c0;
    int C = cb + c;
    int orow = ((C >> 5) << 6) + (C & 31) + (up << 5);
    uint2 v0 = *(const uint2*)&tile[c][h0];
    uint2 v1 = *(const uint2*)&tile[c][h0 + 4];
    uint4 v; v.x = v0.x; v.y = v0.y; v.z = v1.x; v.w = v1.y;
    *(uint4*)(op + (size_t)orow * HDIM + rb + h0) = v;
  }
}

// ---------------- router: 1 wave per token, fp32 logits, top-2
__global__ __launch_bounds__(256)
void router_kernel(const float* __restrict__ tokens, const float* __restrict__ wr,
                   int* __restrict__ topsel, float* __restrict__ wts) {
  int lane = threadIdx.x & 63;
  int t = (blockIdx.x << 2) + (threadIdx.x >> 6);
  const float* tok = tokens + (size_t)t * HDIM;
  float acc[8];
#pragma unroll
  for (int i = 0; i < 8; ++i) acc[i] = 0.f;
#pragma unroll
  for (int j = 0; j < 4; ++j) {
    int h0 = j * 256 + lane * 4;
    float4 tv = *(const float4*)(tok + h0);
    const float* w = wr + (size_t)h0 * 8;
#pragma unroll
    for (int q = 0; q < 4; ++q) {
      float xv = ((const float*)&tv)[q];
      float4 wa = *(const float4*)(w + q * 8);
      float4 wb = *(const float4*)(w + q * 8 + 4);
      acc[0] += xv * wa.x; acc[1] += xv * wa.y; acc[2] += xv * wa.z; acc[3] += xv * wa.w;
      acc[4] += xv * wb.x; acc[5] += xv * wb.y; acc[6] += xv * wb.z; acc[7] += xv * wb.w;
    }
  }
#pragma unroll
  for (int off = 1; off < 64; off <<= 1) {
#pragma unroll
    for (int i = 0; i < 8; ++i) acc[i] += __shfl_xor(acc[i], off, 64);
  }
  if (lane == 0) {
    int e0 = 0; float v0 = acc[0];
#pragma unroll
    for (int i = 1; i < 8; ++i) if (acc[i] > v0) { v0 = acc[i]; e0 = i; }
    int e1 = -1; float v1 = -3.4e38f;
#pragma unroll
    for (int i = 0; i < 8; ++i) if (i != e0 && acc[i] > v1) { v1 = acc[i]; e1 = i; }
    float w0 = 1.f / (1.f + __expf(v1 - v0));
    topsel[t * 2] = e0; topsel[t * 2 + 1] = e1;
    wts[t * 2] = w0;    wts[t * 2 + 1] = 1.f - w0;
  }
}

// ---------------- dispatch: ordered ranks per (k,e), capacity drop
__global__ void dispatch_kernel(const int* __restrict__ topsel, int* __restrict__ slot,
                                int* __restrict__ src_tok) {
  int k = blockIdx.x >> 3, e = blockIdx.x & 7;
  int lane = threadIdx.x;  // 64 threads
  unsigned long long lmask = (lane == 0) ? 0ull : (~0ull >> (64 - lane));
  int base = 0;
  if (k == 1) {
    for (int t0 = 0; t0 < T_TOK; t0 += 64) {
      int ch = topsel[(t0 + lane) * 2];
      base += __popcll(__ballot(ch == e));
    }
  }
  for (int t0 = 0; t0 < T_TOK; t0 += 64) {
    int t = t0 + lane;
    int ch = topsel[t * 2 + k];
    unsigned long long m = __ballot(ch == e);
    if (ch == e) {
      int r = base + __popcll(m & lmask);
      if (r < CAP) { slot[t * 2 + k] = r; src_tok[e * CAP + r] = t; }
      else         { slot[t * 2 + k] = -1; }
    }
    base += __popcll(m);
  }
}

// ---------------- gather tokens -> bf16 x (E*CAP, HDIM); zero unfilled slots
__global__ __launch_bounds__(128)
void gather_x(const float* __restrict__ tokens, const int* __restrict__ src_tok,
              unsigned short* __restrict__ x) {
  int s = blockIdx.x;
  int t = src_tok[s];
  unsigned short* xr = x + (size_t)s * HDIM + threadIdx.x * 8;
  uint4 v = {0u, 0u, 0u, 0u};
  if (t >= 0) {
    const float* tr = tokens + (size_t)t * HDIM + threadIdx.x * 8;
    float4 a = *(const float4*)tr;
    float4 b = *(const float4*)(tr + 4);
    v.x = (unsigned)f2bf(a.x) | ((unsigned)f2bf(a.y) << 16);
    v.y = (unsigned)f2bf(a.z) | ((unsigned)f2bf(a.w) << 16);
    v.z = (unsigned)f2bf(b.x) | ((unsigned)f2bf(b.y) << 16);
    v.w = (unsigned)f2bf(b.z) | ((unsigned)f2bf(b.w) << 16);
  }
  *(uint4*)xr = v;
}

// ================= 256x256x64 pipelined GEMM mainloop =================
// LDS tiles [256][64] bf16, XOR-swizzled slots: LDS[row][s] holds global[row][s^(row&7)]
// (16B slot granularity). Stage: linear LDS dest + pre-swizzled global source.
__device__ __forceinline__ void stage_half(const unsigned short* g, int ld, int rw0, int kc,
                                           unsigned short* dst, int tid) {
  int i0 = tid, i1 = tid + 512;
  int r0 = i0 >> 3, s0 = (i0 & 7) ^ (r0 & 7);
  int r1 = i1 >> 3, s1 = (i1 & 7) ^ (r1 & 7);
  gload_lds16(g + (size_t)(rw0 + r0) * ld + kc + s0 * 8, dst + i0 * 8);
  gload_lds16(g + (size_t)(rw0 + r1) * ld + kc + s1 * 8, dst + i1 * 8);
}

__device__ __forceinline__ bf16x8 fragld(const unsigned short* t, int row, int s16) {
  return *(const bf16x8*)(t + row * 64 + ((s16 ^ (row & 7)) << 3));
}

#define MFMA_BF16 __builtin_amdgcn_mfma_f32_16x16x32_bf16
#define VMCNT4()  asm volatile("s_waitcnt vmcnt(4)" ::: "memory")
#define BAR()     __builtin_amdgcn_s_barrier()

__device__ __forceinline__ void gemm_mainloop(const unsigned short* __restrict__ Ag,
                                              const unsigned short* __restrict__ Bg,
                                              int lda, int ldb, int k0, int nkt,
                                              unsigned short* As, unsigned short* Bs,
                                              f32x4 acc[8][4]) {
  int tid = threadIdx.x;
  int lane = tid & 63, wid = tid >> 6;
  int wr = wid >> 2, wc = wid & 3;
  int fr = lane & 15, fg = lane >> 4;
  int arow = wr * 128 + fr;
  int brow = wc * 64 + fr;

  // prologue: stage tile 0 into buf 0 (order: Ah0, Bh0, Ah1, Bh1)
  stage_half(Ag, lda, 0,   k0, As, tid);
  stage_half(Bg, ldb, 0,   k0, Bs, tid);
  stage_half(Ag, lda, 128, k0, As + 128 * 64, tid);
  stage_half(Bg, ldb, 128, k0, Bs + 128 * 64, tid);
  VMCNT4();   // Ah0,Bh0 landed; Ah1,Bh1 in flight
  BAR();

  for (int t = 0; t < nkt; ++t) {
    unsigned short* Ac = As + (t & 1) * 16384;
    unsigned short* Bc = Bs + (t & 1) * 16384;
    unsigned short* An = As + ((t + 1) & 1) * 16384;
    unsigned short* Bn = Bs + ((t + 1) & 1) * 16384;
    int tn = (t + 1 < nkt) ? t + 1 : t;   // final iter: redundant re-stage (never read)
    int kN = k0 + tn * 64;
    bf16x8 af[4][2], bv[2][2];

    // ---- Phase 1: quadrant m0-3 x n0-1 (reads Ah0,Bh0 cur) ----
    stage_half(Ag, lda, 0, kN, An, tid);
    stage_half(Bg, ldb, 0, kN, Bn, tid);
#pragma unroll
    for (int m = 0; m < 4; ++m) {
      af[m][0] = fragld(Ac, arow + m * 16, fg);
      af[m][1] = fragld(Ac, arow + m * 16, 4 + fg);
    }
#pragma unroll
    for (int n = 0; n < 2; ++n) {
      bv[n][0] = fragld(Bc, brow + n * 16, fg);
      bv[n][1] = fragld(Bc, brow + n * 16, 4 + fg);
    }
    __builtin_amdgcn_s_setprio(1);
#pragma unroll
    for (int m = 0; m < 4; ++m)
#pragma unroll
      for (int n = 0; n < 2; ++n) {
        acc[m][n] = MFMA_BF16(af[m][0], bv[n][0], acc[m][n], 0, 0, 0);
        acc[m][n] = MFMA_BF16(af[m][1], bv[n][1], acc[m][n], 0, 0, 0);
      }
    __builtin_amdgcn_s_setprio(0);
    VMCNT4();   // guarantees Ah1,Bh1 of cur landed
    BAR();

    // ---- Phase 2: m0-3 x n2-3 (reads Ah0,Bh1 cur) ----
    stage_half(Ag, lda, 128, kN, An + 128 * 64, tid);
    stage_half(Bg, ldb, 128, kN, Bn + 128 * 64, tid);
#pragma unroll
    for (int n = 0; n < 2; ++n) {
      bv[n][0] = fragld(Bc, brow + (n + 2) * 16, fg);
      bv[n][1] = fragld(Bc, brow + (n + 2) * 16, 4 + fg);
    }
    __builtin_amdgcn_s_setprio(1);
#pragma unroll
    for (int m = 0; m < 4; ++m)
#pragma unroll
      for (int n = 0; n < 2; ++n) {
        acc[m][n + 2] = MFMA_BF16(af[m][0], bv[n][0], acc[m][n + 2], 0, 0, 0);
        acc[m][n + 2] = MFMA_BF16(af[m][1], bv[n][1], acc[m][n + 2], 0, 0, 0);
      }
    __builtin_amdgcn_s_setprio(0);
    BAR();

    // ---- Phase 3: m4-7 x n2-3 (reads Ah1,Bh1 cur) ----
#pragma unroll
    for (int m = 0; m < 4; ++m) {
      af[m][0] = fragld(Ac, arow + (m + 4) * 16, fg);
      af[m][1] = fragld(Ac, arow + (m + 4) * 16, 4 + fg);
    }
    __builtin_amdgcn_s_setprio(1);
#pragma unroll
    for (int m = 0; m < 4; ++m)
#pragma unroll
      for (int n = 0; n < 2; ++n) {
        acc[m + 4][n + 2] = MFMA_BF16(af[m][0], bv[n][0], acc[m + 4][n + 2], 0, 0, 0);
        acc[m + 4][n + 2] = MFMA_BF16(af[m][1], bv[n][1], acc[m + 4][n + 2], 0, 0, 0);
      }
    __builtin_amdgcn_s_setprio(0);
    BAR();

    // ---- Phase 4: m4-7 x n0-1 (reads Ah1,Bh0 cur) ----
#pragma unroll
    for (int n = 0; n < 2; ++n) {
      bv[n][0] = fragld(Bc, brow + n * 16, fg);
      bv[n][1] = fragld(Bc, brow + n * 16, 4 + fg);
    }
    __builtin_amdgcn_s_setprio(1);
#pragma unroll
    for (int m = 0; m < 4; ++m)
#pragma unroll
      for (int n = 0; n < 2; ++n) {
        acc[m + 4][n] = MFMA_BF16(af[m][0], bv[n][0], acc[m + 4][n], 0, 0, 0);
        acc[m + 4][n] = MFMA_BF16(af[m][1], bv[n][1], acc[m + 4][n], 0, 0, 0);
      }
    __builtin_amdgcn_s_setprio(0);
    VMCNT4();   // guarantees Ah0,Bh0 of next landed
    BAR();
  }
}

// ---------------- GEMM1: h = silu(x@Wg) * (x@Wu), interleaved wgu B (N=8192)
__global__ __launch_bounds__(512, 2)
void gemm1_kernel(const unsigned short* __restrict__ x, const unsigned short* __restrict__ wgu,
                  unsigned short* __restrict__ h) {
  __shared__ unsigned short As[2 * 16384];
  __shared__ unsigned short Bs[2 * 16384];
  int flat = blockIdx.x;                       // 2560 blocks
  int swz = (flat & 7) * 320 + (flat >> 3);    // XCD-chunked: one expert per XCD
  int e = swz / 320, rem = swz % 320;
  int by = rem % 10, bx = rem / 10;            // by fastest: B-panel reuse in L2
  const unsigned short* Ag = x   + ((size_t)e * CAP  + (size_t)by * 256) * HDIM;
  const unsigned short* Bg = wgu + ((size_t)e * 2 * FDIM + (size_t)bx * 256) * HDIM;
  f32x4 acc[8][4];
#pragma unroll
  for (int m = 0; m < 8; ++m)
#pragma unroll
    for (int n = 0; n < 4; ++n) acc[m][n] = (f32x4){0.f, 0.f, 0.f, 0.f};
  gemm_mainloop(Ag, Bg, HDIM, HDIM, 0, HDIM / 64, As, Bs, acc);

  int lane = threadIdx.x & 63, wid = threadIdx.x >> 6;
  int wr = wid >> 2, wc = wid & 3;
  int fr = lane & 15, fg = lane >> 4;
  size_t rbase = (size_t)e * CAP + by * 256 + wr * 128 + fg * 4;
  int cbase = bx * 128 + wc * 32 + fr;
#pragma unroll
  for (int m = 0; m < 8; ++m)
#pragma unroll
    for (int n = 0; n < 2; ++n)
#pragma unroll
      for (int v = 0; v < 4; ++v) {
        float g = acc[m][n][v];
        float u = acc[m][n + 2][v];
        float s = g / (1.f + __expf(-g));
        h[(rbase + m * 16 + v) * FDIM + cbase + n * 16] = f2bf(s * u);
      }
}

// ---------------- GEMM2: y += h @ Wd (K-split x2, fp32 atomic accumulate)
__global__ __launch_bounds__(512, 2)
void gemm2_kernel(const unsigned short* __restrict__ h, const unsigned short* __restrict__ wdT,
                  float* __restrict__ y) {
  __shared__ unsigned short As[2 * 16384];
  __shared__ unsigned short Bs[2 * 16384];
  int flat = blockIdx.x;                       // 640 blocks
  int swz = (flat & 7) * 80 + (flat >> 3);
  int e = swz / 80, rem = swz % 80;
  int by = rem % 10, q = rem / 10;
  int bx = q & 3, ks = q >> 2;
  int k0 = ks * 2048;
  const unsigned short* Ag = h   + ((size_t)e * CAP  + (size_t)by * 256) * FDIM;
  const unsigned short* Bg = wdT + ((size_t)e * HDIM + (size_t)bx * 256) * FDIM;
  f32x4 acc[8][4];
#pragma unroll
  for (int m = 0; m < 8; ++m)
#pragma unroll
    for (int n = 0; n < 4; ++n) acc[m][n] = (f32x4){0.f, 0.f, 0.f, 0.f};
  gemm_mainloop(Ag, Bg, FDIM, FDIM, k0, 2048 / 64, As, Bs, acc);

  int lane = threadIdx.x & 63, wid = threadIdx.x >> 6;
  int wr = wid >> 2, wc = wid & 3;
  int fr = lane & 15, fg = lane >> 4;
  size_t rbase = (size_t)e * CAP + by * 256 + wr * 128 + fg * 4;
  int cbase = bx * 256 + wc * 64 + fr;
#pragma unroll
  for (int m = 0; m < 8; ++m)
#pragma unroll
    for (int n = 0; n < 4; ++n)
#pragma unroll
      for (int v = 0; v < 4; ++v)
        atomicAdd(&y[(rbase + m * 16 + v) * HDIM + cbase + n * 16], acc[m][n][v]);
}

// ---------------- combine: out[t] = sum_k w_k * y[e_k, slot_k]
__global__ __launch_bounds__(256)
void combine_kernel(const float* __restrict__ y, const int* __restrict__ topsel,
                    const int* __restrict__ slot, const float* __restrict__ wts,
                    float* __restrict__ out) {
  int t = blockIdx.x;
  int i = threadIdx.x * 4;
  float4 s = {0.f, 0.f, 0.f, 0.f};
#pragma unroll
  for (int k = 0; k < 2; ++k) {
    int sl = slot[t * 2 + k];
    if (sl >= 0) {
      int e = topsel[t * 2 + k];
      float w = wts[t * 2 + k];
      float4 v = *(const float4*)(y + ((size_t)e * CAP + sl) * HDIM + i);
      s.x += w * v.x; s.y += w * v.y; s.z += w * v.z; s.w += w * v.w;
    }
  }
  *(float4*)(out + (size_t)t * HDIM + i) = s;
}

extern "C" void kernel_launch(void* const* d_in, const int* in_sizes, int n_in,
                              void* d_out, int out_size, void* d_ws, size_t ws_size,
                              hipStream_t stream) {
  const float* tokens   = (const float*)d_in[0];
  const float* w_router = (const float*)d_in[1];
  const float* w_gate   = (const float*)d_in[2];
  const float* w_up     = (const float*)d_in[3];
  const float* w_down   = (const float*)d_in[4];
  float* out = (float*)d_out;
  char* ws = (char*)d_ws;

  const size_t WGU = (size_t)NE * 2 * FDIM * HDIM * 2;  // 128 MiB interleaved gate/up bf16
  const size_t WD  = (size_t)NE * HDIM * FDIM * 2;      // 64 MiB
  const size_t XB  = (size_t)NE * CAP * HDIM * 2;       // 40 MiB
  const size_t HB  = (size_t)NE * CAP * FDIM * 2;       // 160 MiB
  unsigned short* wguT = (unsigned short*)(ws);
  unsigned short* wdT  = (unsigned short*)(ws + WGU);
  unsigned short* xbuf = (unsigned short*)(ws + WGU + WD);
  unsigned short* hbuf = (unsigned short*)(ws + WGU + WD + XB);
  float* ybuf = (float*)(ws);                           // aliases wguT (dead after gemm1)
  char* tail = ws + WGU + WD + XB + HB;
  int*   topsel  = (int*)tail;
  float* wtsv    = (float*)(tail + (size_t)T_TOK * 2 * 4);
  int*   slotv   = (int*)(tail + (size_t)T_TOK * 2 * 8);
  int*   src_tok = (int*)(tail + (size_t)T_TOK * 2 * 12);

  hipMemsetAsync(src_tok, 0xFF, (size_t)NE * CAP * 4, stream);

  transpose_cvt_gu<<<dim3(FDIM / 64, HDIM / 64, NE), 256, 0, stream>>>(w_gate, wguT, 0);
  transpose_cvt_gu<<<dim3(FDIM / 64, HDIM / 64, NE), 256, 0, stream>>>(w_up,   wguT, 1);
  transpose_cvt<<<dim3(HDIM / 64, FDIM / 64, NE), 256, 0, stream>>>(w_down, wdT, FDIM, HDIM);

  router_kernel<<<T_TOK / 4, 256, 0, stream>>>(tokens, w_router, topsel, wtsv);
  dispatch_kernel<<<16, 64, 0, stream>>>(topsel, slotv, src_tok);
  gather_x<<<NE * CAP, 128, 0, stream>>>(tokens, src_tok, xbuf);

  gemm1_kernel<<<2560, 512, 0, stream>>>(xbuf, wguT, hbuf);

  hipMemsetAsync(ybuf, 0, (size_t)NE * CAP * HDIM * 4, stream);
  gemm2_kernel<<<640, 512, 0, stream>>>(hbuf, wdT, ybuf);

  combine_kernel<<<T_TOK, 256, 0, stream>>>(ybuf, topsel, slotv, wtsv, out);
}

// Round 3
// 839.213 us; speedup vs baseline: 1.3470x; 1.3470x over previous
//
#include <hip/hip_runtime.h>
#include <hip/hip_bf16.h>
#include <stdint.h>

#define T_TOK 16384
#define HDIM  1024
#define FDIM  4096
#define NE    8
#define CAP   2560   // ceil(1.25 * 16384 / 8)

typedef __attribute__((ext_vector_type(8))) __bf16 bf16x8;
typedef __attribute__((ext_vector_type(4))) float  f32x4;

__device__ __forceinline__ unsigned short f2bf(float f) {
  union { float f; unsigned u; } c; c.f = f;
  unsigned u = c.u;
  return (unsigned short)((u + 0x7FFFu + ((u >> 16) & 1u)) >> 16);
}

__device__ __forceinline__ void gload_lds16(const void* g, void* lds) {
  __builtin_amdgcn_global_load_lds((const __attribute__((address_space(1))) void*)g,
                                   (__attribute__((address_space(3))) void*)lds,
                                   16, 0, 0);
}

// ---------------- transpose + fp32->bf16 convert: in (E,R,Cc) f32 -> out (E,Cc,R) bf16
__global__ __launch_bounds__(256)
void transpose_cvt(const float* __restrict__ in, unsigned short* __restrict__ out,
                   int R, int Cc) {
  __shared__ unsigned short tile[64][68];
  int e  = blockIdx.z;
  int rb = blockIdx.y << 6, cb = blockIdx.x << 6;
  const float* inp = in + (size_t)e * R * Cc;
  unsigned short* op = out + (size_t)e * R * Cc;
  int lc  = threadIdx.x & 63;
  int lr0 = threadIdx.x >> 6;
#pragma unroll
  for (int rr = 0; rr < 64; rr += 4) {
    int r = rr + lr0;
    float v = inp[(size_t)(rb + r) * Cc + cb + lc];
    tile[lc][r] = f2bf(v);
  }
  __syncthreads();
  int c0 = threadIdx.x >> 3;
  int h0 = (threadIdx.x & 7) << 3;
#pragma unroll
  for (int cc = 0; cc < 64; cc += 32) {
    int c = cc + c0;
    uint2 v0 = *(const uint2*)&tile[c][h0];
    uint2 v1 = *(const uint2*)&tile[c][h0 + 4];
    uint4 v; v.x = v0.x; v.y = v0.y; v.z = v1.x; v.w = v1.y;
    *(uint4*)(op + (size_t)(cb + c) * R + rb + h0) = v;
  }
}

// ---------------- transpose gate/up into interleaved wgu: rows (grp*64 + 0..31)=gate, (+32..63)=up
__global__ __launch_bounds__(256)
void transpose_cvt_gu(const float* __restrict__ in, unsigned short* __restrict__ out, int up) {
  __shared__ unsigned short tile[64][68];
  int e  = blockIdx.z;
  int rb = blockIdx.y << 6, cb = blockIdx.x << 6;
  const float* inp = in + (size_t)e * HDIM * FDIM;
  unsigned short* op = out + (size_t)e * 2 * FDIM * HDIM;
  int lc  = threadIdx.x & 63;
  int lr0 = threadIdx.x >> 6;
#pragma unroll
  for (int rr = 0; rr < 64; rr += 4) {
    int r = rr + lr0;
    float v = inp[(size_t)(rb + r) * FDIM + cb + lc];
    tile[lc][r] = f2bf(v);
  }
  __syncthreads();
  int c0 = threadIdx.x >> 3;
  int h0 = (threadIdx.x & 7) << 3;
#pragma unroll
  for (int cc = 0; cc < 64; cc += 32) {
    int c = cc + c0;
    int C = cb + c;
    int orow = ((C >> 5) << 6) + (C & 31) + (up << 5);
    uint2 v0 = *(const uint2*)&tile[c][h0];
    uint2 v1 = *(const uint2*)&tile[c][h0 + 4];
    uint4 v; v.x = v0.x; v.y = v0.y; v.z = v1.x; v.w = v1.y;
    *(uint4*)(op + (size_t)orow * HDIM + rb + h0) = v;
  }
}

// ---------------- router: 1 wave per token, fp32 logits, top-2
__global__ __launch_bounds__(256)
void router_kernel(const float* __restrict__ tokens, const float* __restrict__ wr,
                   int* __restrict__ topsel, float* __restrict__ wts) {
  int lane = threadIdx.x & 63;
  int t = (blockIdx.x << 2) + (threadIdx.x >> 6);
  const float* tok = tokens + (size_t)t * HDIM;
  float acc[8];
#pragma unroll
  for (int i = 0; i < 8; ++i) acc[i] = 0.f;
#pragma unroll
  for (int j = 0; j < 4; ++j) {
    int h0 = j * 256 + lane * 4;
    float4 tv = *(const float4*)(tok + h0);
    const float* w = wr + (size_t)h0 * 8;
#pragma unroll
    for (int q = 0; q < 4; ++q) {
      float xv = ((const float*)&tv)[q];
      float4 wa = *(const float4*)(w + q * 8);
      float4 wb = *(const float4*)(w + q * 8 + 4);
      acc[0] += xv * wa.x; acc[1] += xv * wa.y; acc[2] += xv * wa.z; acc[3] += xv * wa.w;
      acc[4] += xv * wb.x; acc[5] += xv * wb.y; acc[6] += xv * wb.z; acc[7] += xv * wb.w;
    }
  }
#pragma unroll
  for (int off = 1; off < 64; off <<= 1) {
#pragma unroll
    for (int i = 0; i < 8; ++i) acc[i] += __shfl_xor(acc[i], off, 64);
  }
  if (lane == 0) {
    int e0 = 0; float v0 = acc[0];
#pragma unroll
    for (int i = 1; i < 8; ++i) if (acc[i] > v0) { v0 = acc[i]; e0 = i; }
    int e1 = -1; float v1 = -3.4e38f;
#pragma unroll
    for (int i = 0; i < 8; ++i) if (i != e0 && acc[i] > v1) { v1 = acc[i]; e1 = i; }
    float w0 = 1.f / (1.f + __expf(v1 - v0));
    topsel[t * 2] = e0; topsel[t * 2 + 1] = e1;
    wts[t * 2] = w0;    wts[t * 2 + 1] = 1.f - w0;
  }
}

// ---------------- dispatch: per-expert block; 3-pass (count / scan / assign)
__global__ __launch_bounds__(256)
void dispatch_kernel(const int* __restrict__ topsel, int* __restrict__ slot,
                     int* __restrict__ src_tok) {
  int e = blockIdx.x;           // 8 blocks
  int w = threadIdx.x >> 6, lane = threadIdx.x & 63;
  __shared__ int gcnt[2][256];
  __shared__ int tot[2];
  // pass 1: per-group (64 tokens) counts
#pragma unroll
  for (int k = 0; k < 2; ++k)
    for (int g = w; g < 256; g += 4) {
      int ch = topsel[(g * 64 + lane) * 2 + k];
      unsigned long long m = __ballot(ch == e);
      if (lane == 0) gcnt[k][g] = __popcll(m);
    }
  __syncthreads();
  // pass 2: exclusive scan of 256 group counts (wave k handles k)
  if (w < 2) {
    int k = w;
    int c0 = gcnt[k][lane * 4], c1 = gcnt[k][lane * 4 + 1];
    int c2 = gcnt[k][lane * 4 + 2], c3 = gcnt[k][lane * 4 + 3];
    int s = c0 + c1 + c2 + c3;
    int inc = s;
#pragma unroll
    for (int off = 1; off < 64; off <<= 1) {
      int v = __shfl_up(inc, off, 64);
      if (lane >= off) inc += v;
    }
    int base = inc - s;
    gcnt[k][lane * 4] = base;
    gcnt[k][lane * 4 + 1] = base + c0;
    gcnt[k][lane * 4 + 2] = base + c0 + c1;
    gcnt[k][lane * 4 + 3] = base + c0 + c1 + c2;
    if (lane == 63) tot[k] = inc;
  }
  __syncthreads();
  // pass 3: assign ranks (reference order: k=0 block then k=1 block)
#pragma unroll
  for (int k = 0; k < 2; ++k) {
    int kbase = (k == 1) ? tot[0] : 0;
    for (int g = w; g < 256; g += 4) {
      int t = g * 64 + lane;
      int ch = topsel[t * 2 + k];
      unsigned long long m = __ballot(ch == e);
      if (ch == e) {
        unsigned long long lmask = lane ? (~0ull >> (64 - lane)) : 0ull;
        int r = kbase + gcnt[k][g] + __popcll(m & lmask);
        if (r < CAP) { slot[t * 2 + k] = r; src_tok[e * CAP + r] = t; }
        else         { slot[t * 2 + k] = -1; }
      }
    }
  }
}

// ---------------- gather tokens -> bf16 x (E*CAP, HDIM); zero unfilled slots
__global__ __launch_bounds__(128)
void gather_x(const float* __restrict__ tokens, const int* __restrict__ src_tok,
              unsigned short* __restrict__ x) {
  int s = blockIdx.x;
  int t = src_tok[s];
  unsigned short* xr = x + (size_t)s * HDIM + threadIdx.x * 8;
  uint4 v = {0u, 0u, 0u, 0u};
  if (t >= 0) {
    const float* tr = tokens + (size_t)t * HDIM + threadIdx.x * 8;
    float4 a = *(const float4*)tr;
    float4 b = *(const float4*)(tr + 4);
    v.x = (unsigned)f2bf(a.x) | ((unsigned)f2bf(a.y) << 16);
    v.y = (unsigned)f2bf(a.z) | ((unsigned)f2bf(a.w) << 16);
    v.z = (unsigned)f2bf(b.x) | ((unsigned)f2bf(b.y) << 16);
    v.w = (unsigned)f2bf(b.z) | ((unsigned)f2bf(b.w) << 16);
  }
  *(uint4*)xr = v;
}

// ================= BK=32 triple-buffered pipelined GEMM mainloop =================
// A-tile: (MF*32) x 32 bf16, B-tile: 256 x 32 bf16, both LINEAR in LDS (at BK=32 the
// k-slot fg*16B spreads a wave's frag reads uniformly over all 32 banks -> no swizzle).
// Triple-buffer: tile T staged during window T-2 -> every load has >= 2 windows to land;
// vmcnt(L) at window end retires exactly tile T+1 (never drains, strictly race-free).
template<int MF>   // m-frags per wave: 8 (BM=256) or 4 (BM=128)
__device__ __forceinline__ void gemm_mainloop(const unsigned short* __restrict__ Ag,
                                              const unsigned short* __restrict__ Bg,
                                              int lda, int ldb, int nkt,
                                              unsigned short* lds, f32x4 (&acc)[MF][4]) {
  constexpr int AEL = MF * 32 * 32;      // A tile elements
  constexpr int TEL = AEL + 256 * 32;    // A+B tile elements
  constexpr int NLA = MF / 4;            // A gload_lds per thread per tile (2 or 1)
  constexpr int L   = NLA + 2;           // total loads per thread per tile
  int tid = threadIdx.x, lane = tid & 63, wid = tid >> 6;
  int wr = wid >> 2, wc = wid & 3, fr = lane & 15, fg = lane >> 4;
  int arow = wr * (MF * 16) + fr;
  int brow = wc * 64 + fr;
  int srow = tid >> 2, sc = (tid & 3) * 8;

  auto stA = [&](int t, int lo) {
    int ks = (t < nkt ? t : nkt - 1) * 32;
    gload_lds16(Ag + (size_t)(lo * 128 + srow) * lda + ks + sc,
                lds + (t % 3) * TEL + (lo * 128 + srow) * 32 + sc);
  };
  auto stB = [&](int t, int lo) {
    int ks = (t < nkt ? t : nkt - 1) * 32;
    gload_lds16(Bg + (size_t)(lo * 128 + srow) * ldb + ks + sc,
                lds + (t % 3) * TEL + AEL + (lo * 128 + srow) * 32 + sc);
  };

  // prologue: stage tiles 0 and 1
#pragma unroll
  for (int t = 0; t < 2; ++t) {
#pragma unroll
    for (int lo = 0; lo < NLA; ++lo) stA(t, lo);
    stB(t, 0); stB(t, 1);
  }
  if constexpr (L == 4) asm volatile("s_waitcnt vmcnt(4)" ::: "memory");
  else                  asm volatile("s_waitcnt vmcnt(3)" ::: "memory");
  __builtin_amdgcn_s_barrier();

  for (int t = 0; t < nkt; ++t) {
    const unsigned short* Ab = lds + (t % 3) * TEL;
    const unsigned short* Bb = Ab + AEL;
    bf16x8 bv[4], af[MF / 2];
    // ---- phase 1: B-frags (held for both phases) + first m-half ----
#pragma unroll
    for (int n = 0; n < 4; ++n)
      bv[n] = *(const bf16x8*)(Bb + (brow + n * 16) * 32 + fg * 8);
#pragma unroll
    for (int m = 0; m < MF / 2; ++m)
      af[m] = *(const bf16x8*)(Ab + (arow + m * 16) * 32 + fg * 8);
    if constexpr (MF == 8) { stA(t + 2, 0); stA(t + 2, 1); }
    else                   { stA(t + 2, 0); stB(t + 2, 0); }
    __builtin_amdgcn_s_barrier();
    __builtin_amdgcn_s_setprio(1);
#pragma unroll
    for (int m = 0; m < MF / 2; ++m)
#pragma unroll
      for (int n = 0; n < 4; ++n)
        acc[m][n] = __builtin_amdgcn_mfma_f32_16x16x32_bf16(af[m], bv[n], acc[m][n], 0, 0, 0);
    __builtin_amdgcn_s_setprio(0);
    __builtin_amdgcn_s_barrier();
    // ---- phase 2: second m-half ----
#pragma unroll
    for (int m = 0; m < MF / 2; ++m)
      af[m] = *(const bf16x8*)(Ab + (arow + (MF / 2 + m) * 16) * 32 + fg * 8);
    if constexpr (MF == 8) { stB(t + 2, 0); stB(t + 2, 1); }
    else                   { stB(t + 2, 1); }
    __builtin_amdgcn_s_barrier();
    __builtin_amdgcn_s_setprio(1);
#pragma unroll
    for (int m = 0; m < MF / 2; ++m)
#pragma unroll
      for (int n = 0; n < 4; ++n)
        acc[MF / 2 + m][n] =
            __builtin_amdgcn_mfma_f32_16x16x32_bf16(af[m], bv[n], acc[MF / 2 + m][n], 0, 0, 0);
    __builtin_amdgcn_s_setprio(0);
    if constexpr (L == 4) asm volatile("s_waitcnt vmcnt(4)" ::: "memory");
    else                  asm volatile("s_waitcnt vmcnt(3)" ::: "memory");
    __builtin_amdgcn_s_barrier();
  }
}

// ---------------- GEMM1: h = silu(x@Wg) * (x@Wu), interleaved wgu B; BM=256,BN=256
__global__ __launch_bounds__(512, 2)
void gemm1_kernel(const unsigned short* __restrict__ x, const unsigned short* __restrict__ wgu,
                  unsigned short* __restrict__ h) {
  __shared__ unsigned short lds[3 * (256 * 32 + 256 * 32)];
  int flat = blockIdx.x;                 // 2560 blocks
  int e = flat & 7, idx = flat >> 3;     // expert per XCD
  int c = idx >> 4, i = idx & 15;        // chunks of 16 blocks (8bx x 2by)
  int cbx = c / 5, cby = c % 5;          // cby fastest: B-panels stay hot in L2
  int bx = cbx * 8 + (i & 7), by = cby * 2 + (i >> 3);
  const unsigned short* Ag = x   + ((size_t)e * CAP + (size_t)by * 256) * HDIM;
  const unsigned short* Bg = wgu + ((size_t)e * 2 * FDIM + (size_t)bx * 256) * HDIM;
  f32x4 acc[8][4];
#pragma unroll
  for (int m = 0; m < 8; ++m)
#pragma unroll
    for (int n = 0; n < 4; ++n) acc[m][n] = (f32x4){0.f, 0.f, 0.f, 0.f};
  gemm_mainloop<8>(Ag, Bg, HDIM, HDIM, HDIM / 32, lds, acc);

  int lane = threadIdx.x & 63, wid = threadIdx.x >> 6;
  int wr = wid >> 2, wc = wid & 3, fr = lane & 15, fg = lane >> 4;
  size_t rbase = (size_t)e * CAP + by * 256 + wr * 128 + fg * 4;
  int cb = bx * 128 + wc * 32 + fr;
#pragma unroll
  for (int m = 0; m < 8; ++m)
#pragma unroll
    for (int n = 0; n < 2; ++n)
#pragma unroll
      for (int v = 0; v < 4; ++v) {
        float g = acc[m][n][v], u = acc[m][n + 2][v];
        float s = g / (1.f + __expf(-g));
        h[(rbase + m * 16 + v) * FDIM + cb + n * 16] = f2bf(s * u);
      }
}

// ---------------- GEMM2: y = h @ Wd; BM=128,BN=256, plain fp32 stores
__global__ __launch_bounds__(512, 4)
void gemm2_kernel(const unsigned short* __restrict__ h, const unsigned short* __restrict__ wdT,
                  float* __restrict__ y) {
  __shared__ unsigned short lds[3 * (128 * 32 + 256 * 32)];
  int flat = blockIdx.x;                 // 640 blocks
  int e = flat & 7, idx = flat >> 3;     // [0,80)
  int bx = idx & 3, by = idx >> 2;       // bx fastest: A-panel shared in L2
  const unsigned short* Ag = h   + ((size_t)e * CAP  + (size_t)by * 128) * FDIM;
  const unsigned short* Bg = wdT + ((size_t)e * HDIM + (size_t)bx * 256) * FDIM;
  f32x4 acc[4][4];
#pragma unroll
  for (int m = 0; m < 4; ++m)
#pragma unroll
    for (int n = 0; n < 4; ++n) acc[m][n] = (f32x4){0.f, 0.f, 0.f, 0.f};
  gemm_mainloop<4>(Ag, Bg, FDIM, FDIM, FDIM / 32, lds, acc);

  int lane = threadIdx.x & 63, wid = threadIdx.x >> 6;
  int wr = wid >> 2, wc = wid & 3, fr = lane & 15, fg = lane >> 4;
  size_t rbase = (size_t)e * CAP + by * 128 + wr * 64 + fg * 4;
  int cb = bx * 256 + wc * 64 + fr;
#pragma unroll
  for (int m = 0; m < 4; ++m)
#pragma unroll
    for (int n = 0; n < 4; ++n)
#pragma unroll
      for (int v = 0; v < 4; ++v)
        y[(rbase + m * 16 + v) * HDIM + cb + n * 16] = acc[m][n][v];
}

// ---------------- combine: out[t] = sum_k w_k * y[e_k, slot_k]
__global__ __launch_bounds__(256)
void combine_kernel(const float* __restrict__ y, const int* __restrict__ topsel,
                    const int* __restrict__ slot, const float* __restrict__ wts,
                    float* __restrict__ out) {
  int t = blockIdx.x;
  int i = threadIdx.x * 4;
  float4 s = {0.f, 0.f, 0.f, 0.f};
#pragma unroll
  for (int k = 0; k < 2; ++k) {
    int sl = slot[t * 2 + k];
    if (sl >= 0) {
      int e = topsel[t * 2 + k];
      float w = wts[t * 2 + k];
      float4 v = *(const float4*)(y + ((size_t)e * CAP + sl) * HDIM + i);
      s.x += w * v.x; s.y += w * v.y; s.z += w * v.z; s.w += w * v.w;
    }
  }
  *(float4*)(out + (size_t)t * HDIM + i) = s;
}

extern "C" void kernel_launch(void* const* d_in, const int* in_sizes, int n_in,
                              void* d_out, int out_size, void* d_ws, size_t ws_size,
                              hipStream_t stream) {
  const float* tokens   = (const float*)d_in[0];
  const float* w_router = (const float*)d_in[1];
  const float* w_gate   = (const float*)d_in[2];
  const float* w_up     = (const float*)d_in[3];
  const float* w_down   = (const float*)d_in[4];
  float* out = (float*)d_out;
  char* ws = (char*)d_ws;

  const size_t WGU = (size_t)NE * 2 * FDIM * HDIM * 2;  // 128 MiB interleaved gate/up bf16
  const size_t WD  = (size_t)NE * HDIM * FDIM * 2;      // 64 MiB
  const size_t XB  = (size_t)NE * CAP * HDIM * 2;       // 40 MiB
  const size_t HB  = (size_t)NE * CAP * FDIM * 2;       // 160 MiB
  unsigned short* wguT = (unsigned short*)(ws);
  unsigned short* wdT  = (unsigned short*)(ws + WGU);
  unsigned short* xbuf = (unsigned short*)(ws + WGU + WD);
  unsigned short* hbuf = (unsigned short*)(ws + WGU + WD + XB);
  float* ybuf = (float*)(ws);                           // aliases wguT (dead after gemm1)
  char* tail = ws + WGU + WD + XB + HB;
  int*   topsel  = (int*)tail;
  float* wtsv    = (float*)(tail + (size_t)T_TOK * 2 * 4);
  int*   slotv   = (int*)(tail + (size_t)T_TOK * 2 * 8);
  int*   src_tok = (int*)(tail + (size_t)T_TOK * 2 * 12);

  hipMemsetAsync(src_tok, 0xFF, (size_t)NE * CAP * 4, stream);

  transpose_cvt_gu<<<dim3(FDIM / 64, HDIM / 64, NE), 256, 0, stream>>>(w_gate, wguT, 0);
  transpose_cvt_gu<<<dim3(FDIM / 64, HDIM / 64, NE), 256, 0, stream>>>(w_up,   wguT, 1);
  transpose_cvt<<<dim3(HDIM / 64, FDIM / 64, NE), 256, 0, stream>>>(w_down, wdT, FDIM, HDIM);

  router_kernel<<<T_TOK / 4, 256, 0, stream>>>(tokens, w_router, topsel, wtsv);
  dispatch_kernel<<<NE, 256, 0, stream>>>(topsel, slotv, src_tok);
  gather_x<<<NE * CAP, 128, 0, stream>>>(tokens, src_tok, xbuf);

  gemm1_kernel<<<2560, 512, 0, stream>>>(xbuf, wguT, hbuf);
  gemm2_kernel<<<640, 512, 0, stream>>>(hbuf, wdT, ybuf);

  combine_kernel<<<T_TOK, 256, 0, stream>>>(ybuf, topsel, slotv, wtsv, out);
}

// Round 4
// 805.561 us; speedup vs baseline: 1.4032x; 1.0418x over previous
//
#include <hip/hip_runtime.h>
#include <hip/hip_bf16.h>
#include <stdint.h>

#define T_TOK 16384
#define HDIM  1024
#define FDIM  4096
#define NE    8
#define CAP   2560   // ceil(1.25 * 16384 / 8)

typedef __attribute__((ext_vector_type(8))) __bf16 bf16x8;
typedef __attribute__((ext_vector_type(4))) float  f32x4;

#define MFMA_BF16 __builtin_amdgcn_mfma_f32_16x16x32_bf16
#define VMCNT(n)  asm volatile("s_waitcnt vmcnt(" #n ")" ::: "memory")
#define BAR()     __builtin_amdgcn_s_barrier()

__device__ __forceinline__ unsigned short f2bf(float f) {
  union { float f; unsigned u; } c; c.f = f;
  unsigned u = c.u;
  return (unsigned short)((u + 0x7FFFu + ((u >> 16) & 1u)) >> 16);
}

__device__ __forceinline__ void gload_lds16(const void* g, void* lds) {
  __builtin_amdgcn_global_load_lds((const __attribute__((address_space(1))) void*)g,
                                   (__attribute__((address_space(3))) void*)lds,
                                   16, 0, 0);
}

// ---------------- transpose + fp32->bf16 convert: in (E,R,Cc) f32 -> out (E,Cc,R) bf16
__global__ __launch_bounds__(256)
void transpose_cvt(const float* __restrict__ in, unsigned short* __restrict__ out,
                   int R, int Cc) {
  __shared__ unsigned short tile[64][68];
  int e  = blockIdx.z;
  int rb = blockIdx.y << 6, cb = blockIdx.x << 6;
  const float* inp = in + (size_t)e * R * Cc;
  unsigned short* op = out + (size_t)e * R * Cc;
  int lc  = threadIdx.x & 63;
  int lr0 = threadIdx.x >> 6;
#pragma unroll
  for (int rr = 0; rr < 64; rr += 4) {
    int r = rr + lr0;
    float v = inp[(size_t)(rb + r) * Cc + cb + lc];
    tile[lc][r] = f2bf(v);
  }
  __syncthreads();
  int c0 = threadIdx.x >> 3;
  int h0 = (threadIdx.x & 7) << 3;
#pragma unroll
  for (int cc = 0; cc < 64; cc += 32) {
    int c = cc + c0;
    uint2 v0 = *(const uint2*)&tile[c][h0];
    uint2 v1 = *(const uint2*)&tile[c][h0 + 4];
    uint4 v; v.x = v0.x; v.y = v0.y; v.z = v1.x; v.w = v1.y;
    *(uint4*)(op + (size_t)(cb + c) * R + rb + h0) = v;
  }
}

// ---------------- transpose gate/up into interleaved wgu: rows (grp*64 + 0..31)=gate, (+32..63)=up
__global__ __launch_bounds__(256)
void transpose_cvt_gu(const float* __restrict__ in, unsigned short* __restrict__ out, int up) {
  __shared__ unsigned short tile[64][68];
  int e  = blockIdx.z;
  int rb = blockIdx.y << 6, cb = blockIdx.x << 6;
  const float* inp = in + (size_t)e * HDIM * FDIM;
  unsigned short* op = out + (size_t)e * 2 * FDIM * HDIM;
  int lc  = threadIdx.x & 63;
  int lr0 = threadIdx.x >> 6;
#pragma unroll
  for (int rr = 0; rr < 64; rr += 4) {
    int r = rr + lr0;
    float v = inp[(size_t)(rb + r) * FDIM + cb + lc];
    tile[lc][r] = f2bf(v);
  }
  __syncthreads();
  int c0 = threadIdx.x >> 3;
  int h0 = (threadIdx.x & 7) << 3;
#pragma unroll
  for (int cc = 0; cc < 64; cc += 32) {
    int c = cc + c0;
    int C = cb + c;
    int orow = ((C >> 5) << 6) + (C & 31) + (up << 5);
    uint2 v0 = *(const uint2*)&tile[c][h0];
    uint2 v1 = *(const uint2*)&tile[c][h0 + 4];
    uint4 v; v.x = v0.x; v.y = v0.y; v.z = v1.x; v.w = v1.y;
    *(uint4*)(op + (size_t)orow * HDIM + rb + h0) = v;
  }
}

// ---------------- router: 1 wave per token, fp32 logits, top-2
__global__ __launch_bounds__(256)
void router_kernel(const float* __restrict__ tokens, const float* __restrict__ wr,
                   int* __restrict__ topsel, float* __restrict__ wts) {
  int lane = threadIdx.x & 63;
  int t = (blockIdx.x << 2) + (threadIdx.x >> 6);
  const float* tok = tokens + (size_t)t * HDIM;
  float acc[8];
#pragma unroll
  for (int i = 0; i < 8; ++i) acc[i] = 0.f;
#pragma unroll
  for (int j = 0; j < 4; ++j) {
    int h0 = j * 256 + lane * 4;
    float4 tv = *(const float4*)(tok + h0);
    const float* w = wr + (size_t)h0 * 8;
#pragma unroll
    for (int q = 0; q < 4; ++q) {
      float xv = ((const float*)&tv)[q];
      float4 wa = *(const float4*)(w + q * 8);
      float4 wb = *(const float4*)(w + q * 8 + 4);
      acc[0] += xv * wa.x; acc[1] += xv * wa.y; acc[2] += xv * wa.z; acc[3] += xv * wa.w;
      acc[4] += xv * wb.x; acc[5] += xv * wb.y; acc[6] += xv * wb.z; acc[7] += xv * wb.w;
    }
  }
#pragma unroll
  for (int off = 1; off < 64; off <<= 1) {
#pragma unroll
    for (int i = 0; i < 8; ++i) acc[i] += __shfl_xor(acc[i], off, 64);
  }
  if (lane == 0) {
    int e0 = 0; float v0 = acc[0];
#pragma unroll
    for (int i = 1; i < 8; ++i) if (acc[i] > v0) { v0 = acc[i]; e0 = i; }
    int e1 = -1; float v1 = -3.4e38f;
#pragma unroll
    for (int i = 0; i < 8; ++i) if (i != e0 && acc[i] > v1) { v1 = acc[i]; e1 = i; }
    float w0 = 1.f / (1.f + __expf(v1 - v0));
    topsel[t * 2] = e0; topsel[t * 2 + 1] = e1;
    wts[t * 2] = w0;    wts[t * 2 + 1] = 1.f - w0;
  }
}

// ---------------- dispatch: per-expert block; 3-pass (count / scan / assign)
__global__ __launch_bounds__(256)
void dispatch_kernel(const int* __restrict__ topsel, int* __restrict__ slot,
                     int* __restrict__ src_tok) {
  int e = blockIdx.x;           // 8 blocks
  int w = threadIdx.x >> 6, lane = threadIdx.x & 63;
  __shared__ int gcnt[2][256];
  __shared__ int tot[2];
#pragma unroll
  for (int k = 0; k < 2; ++k)
    for (int g = w; g < 256; g += 4) {
      int ch = topsel[(g * 64 + lane) * 2 + k];
      unsigned long long m = __ballot(ch == e);
      if (lane == 0) gcnt[k][g] = __popcll(m);
    }
  __syncthreads();
  if (w < 2) {
    int k = w;
    int c0 = gcnt[k][lane * 4], c1 = gcnt[k][lane * 4 + 1];
    int c2 = gcnt[k][lane * 4 + 2], c3 = gcnt[k][lane * 4 + 3];
    int s = c0 + c1 + c2 + c3;
    int inc = s;
#pragma unroll
    for (int off = 1; off < 64; off <<= 1) {
      int v = __shfl_up(inc, off, 64);
      if (lane >= off) inc += v;
    }
    int base = inc - s;
    gcnt[k][lane * 4] = base;
    gcnt[k][lane * 4 + 1] = base + c0;
    gcnt[k][lane * 4 + 2] = base + c0 + c1;
    gcnt[k][lane * 4 + 3] = base + c0 + c1 + c2;
    if (lane == 63) tot[k] = inc;
  }
  __syncthreads();
#pragma unroll
  for (int k = 0; k < 2; ++k) {
    int kbase = (k == 1) ? tot[0] : 0;
    for (int g = w; g < 256; g += 4) {
      int t = g * 64 + lane;
      int ch = topsel[t * 2 + k];
      unsigned long long m = __ballot(ch == e);
      if (ch == e) {
        unsigned long long lmask = lane ? (~0ull >> (64 - lane)) : 0ull;
        int r = kbase + gcnt[k][g] + __popcll(m & lmask);
        if (r < CAP) { slot[t * 2 + k] = r; src_tok[e * CAP + r] = t; }
        else         { slot[t * 2 + k] = -1; }
      }
    }
  }
}

// ---------------- gather tokens -> bf16 x (E*CAP, HDIM); zero unfilled slots
__global__ __launch_bounds__(128)
void gather_x(const float* __restrict__ tokens, const int* __restrict__ src_tok,
              unsigned short* __restrict__ x) {
  int s = blockIdx.x;
  int t = src_tok[s];
  unsigned short* xr = x + (size_t)s * HDIM + threadIdx.x * 8;
  uint4 v = {0u, 0u, 0u, 0u};
  if (t >= 0) {
    const float* tr = tokens + (size_t)t * HDIM + threadIdx.x * 8;
    float4 a = *(const float4*)tr;
    float4 b = *(const float4*)(tr + 4);
    v.x = (unsigned)f2bf(a.x) | ((unsigned)f2bf(a.y) << 16);
    v.y = (unsigned)f2bf(a.z) | ((unsigned)f2bf(a.w) << 16);
    v.z = (unsigned)f2bf(b.x) | ((unsigned)f2bf(b.y) << 16);
    v.w = (unsigned)f2bf(b.z) | ((unsigned)f2bf(b.w) << 16);
  }
  *(uint4*)xr = v;
}

// ================= 8-phase 256xBN x BK=64 GEMM mainloop =================
// Block C split into 4 quadrants (mh,nh), gray order (0,0),(0,1),(1,1),(1,0):
// each phase reads ONE A-half + ONE B-half; unchanged operand frags held in regs.
// LDS: A,B double-buffered, XOR-swizzled 16B slots (slot ^= row&7) -> conflict-free
// b128 frag reads; staged via inverse-swizzled global source + linear gload_lds dest.
// Stage 1 half/phase: P1:B0(t+1) P2:A1(t+1) P3:A0(t+2) P4:B1(t+2); counted vmcnt
// at every phase end retires loads issued >=3 phases back (never drains to 0).
template<int BN>   // 256 (gemm1) or 128 (gemm2)
__device__ __forceinline__ void mainloop8(const unsigned short* __restrict__ Ag,
                                          const unsigned short* __restrict__ Bg,
                                          int lda, int ldb, int nkt,
                                          unsigned short* lds, f32x4 (&acc)[4][BN / 32]) {
  constexpr int NF  = BN / 64;        // n-frags per wave per quadrant
  constexpr int AEL = 256 * 64;       // elements per A tile buffer
  constexpr int BEL = BN * 64;
  int tid = threadIdx.x, lane = tid & 63, wid = tid >> 6;
  int qr = wid >> 1, qc = wid & 1;
  int fr = lane & 15, fg = lane >> 4;

  auto stA = [&](int t, int mh) {     // A-half mh (128 rows) of tile t -> buf t&1
    int kt = (t < nkt ? t : nkt - 1) * 64;
    unsigned short* dst = lds + (t & 1) * AEL + mh * 8192;
#pragma unroll
    for (int l = 0; l < 2; ++l) {
      int idx = l * 512 + tid;
      int row = idx >> 3;
      int sl  = (idx & 7) ^ (row & 7);
      gload_lds16(Ag + (size_t)(mh * 128 + row) * lda + kt + sl * 8, dst + idx * 8);
    }
  };
  auto stB = [&](int t, int nh) {     // B-half nh (BN/2 rows) of tile t -> buf t&1
    int kt = (t < nkt ? t : nkt - 1) * 64;
    unsigned short* dst = lds + 2 * AEL + (t & 1) * BEL + nh * (BN / 2) * 64;
#pragma unroll
    for (int l = 0; l < BN / 128; ++l) {
      int idx = l * 512 + tid;
      int row = idx >> 3;
      int sl  = (idx & 7) ^ (row & 7);
      gload_lds16(Bg + (size_t)(nh * (BN / 2) + row) * ldb + kt + sl * 8, dst + idx * 8);
    }
  };

  const unsigned short* Ab = lds;
  const unsigned short* Bb = lds + 2 * AEL;
  auto ldfrag = [&](const unsigned short* buf, int row, int kk) -> bf16x8 {
    return *(const bf16x8*)(buf + row * 64 + ((((kk << 2) | fg) ^ (row & 7)) << 3));
  };
  bf16x8 afr[2][2], bfr[NF][2];
  auto loadA = [&](int mh) {
#pragma unroll
    for (int mf = 0; mf < 2; ++mf)
#pragma unroll
      for (int kk = 0; kk < 2; ++kk)
        afr[mf][kk] = ldfrag(Ab, mh * 128 + qr * 32 + mf * 16 + fr, kk);
  };
  auto loadB = [&](int nh) {
#pragma unroll
    for (int nf = 0; nf < NF; ++nf)
#pragma unroll
      for (int kk = 0; kk < 2; ++kk)
        bfr[nf][kk] = ldfrag(Bb, nh * (BN / 2) + qc * (NF * 16) + nf * 16 + fr, kk);
  };
  auto mmac = [&](int mh, int nh) {
    __builtin_amdgcn_s_setprio(1);
#pragma unroll
    for (int mf = 0; mf < 2; ++mf)
#pragma unroll
      for (int nf = 0; nf < NF; ++nf)
#pragma unroll
        for (int kk = 0; kk < 2; ++kk)
          acc[mh * 2 + mf][nh * NF + nf] =
              MFMA_BF16(afr[mf][kk], bfr[nf][kk], acc[mh * 2 + mf][nh * NF + nf], 0, 0, 0);
    __builtin_amdgcn_s_setprio(0);
  };

  // prologue: A0(0) B0(0) B1(0) A1(0) A0(1) B1(1)
  stA(0, 0); stB(0, 0); stB(0, 1); stA(0, 1); stA(1, 0); stB(1, 1);
  if constexpr (BN == 256) VMCNT(8); else VMCNT(6);
  BAR();

  for (int t = 0; t < nkt; ++t) {
    Ab = lds + (t & 1) * AEL;
    Bb = lds + 2 * AEL + (t & 1) * BEL;
    // P1: Q(0,0)
    loadA(0); loadB(0); stB(t + 1, 0);
    BAR();
    mmac(0, 0);
    if constexpr (BN == 256) VMCNT(6); else VMCNT(4);
    BAR();
    // P2: Q(0,1)
    loadB(1); stA(t + 1, 1);
    BAR();
    mmac(0, 1);
    if constexpr (BN == 256) VMCNT(6); else VMCNT(4);
    BAR();
    // P3: Q(1,1)
    loadA(1); stA(t + 2, 0);
    BAR();
    mmac(1, 1);
    if constexpr (BN == 256) VMCNT(6); else VMCNT(5);
    BAR();
    // P4: Q(1,0)
    loadB(0); stB(t + 2, 1);
    BAR();
    mmac(1, 0);
    if constexpr (BN == 256) VMCNT(6); else VMCNT(5);
    BAR();
  }
}

// ---------------- GEMM1: h = silu(x@Wg) * (x@Wu), interleaved wgu B; 256x256
__global__ __launch_bounds__(512, 1)
void gemm1_kernel(const unsigned short* __restrict__ x, const unsigned short* __restrict__ wgu,
                  unsigned short* __restrict__ h) {
  __shared__ unsigned short lds[2 * 256 * 64 + 2 * 256 * 64];
  int flat = blockIdx.x;                 // 2560 blocks
  int e = flat & 7, idx = flat >> 3;     // expert per XCD
  int c = idx >> 4, i = idx & 15;        // chunks of 16 blocks (8bx x 2by)
  int cbx = c / 5, cby = c % 5;
  int bx = cbx * 8 + (i & 7), by = cby * 2 + (i >> 3);
  const unsigned short* Ag = x   + ((size_t)e * CAP + (size_t)by * 256) * HDIM;
  const unsigned short* Bg = wgu + ((size_t)e * 2 * FDIM + (size_t)bx * 256) * HDIM;
  f32x4 acc[4][8];
#pragma unroll
  for (int m = 0; m < 4; ++m)
#pragma unroll
    for (int n = 0; n < 8; ++n) acc[m][n] = (f32x4){0.f, 0.f, 0.f, 0.f};
  mainloop8<256>(Ag, Bg, HDIM, HDIM, HDIM / 64, lds, acc);

  int lane = threadIdx.x & 63, wid = threadIdx.x >> 6;
  int qr = wid >> 1, qc = wid & 1, fr = lane & 15, fg = lane >> 4;
  size_t rbase = (size_t)e * CAP + by * 256;
#pragma unroll
  for (int mi = 0; mi < 4; ++mi) {
    int row0 = (mi >> 1) * 128 + qr * 32 + (mi & 1) * 16 + fg * 4;
#pragma unroll
    for (int nh = 0; nh < 2; ++nh)
#pragma unroll
      for (int nf = 0; nf < 2; ++nf) {
        int fcol = bx * 128 + (nh * 2 + qc) * 32 + nf * 16 + fr;
#pragma unroll
        for (int v = 0; v < 4; ++v) {
          float g = acc[mi][nh * 4 + nf][v];
          float u = acc[mi][nh * 4 + nf + 2][v];
          float s = g / (1.f + __expf(-g));
          h[(rbase + row0 + v) * FDIM + fcol] = f2bf(s * u);
        }
      }
  }
}

// ---------------- GEMM2: y = h @ Wd; 256x128, plain fp32 stores
__global__ __launch_bounds__(512, 1)
void gemm2_kernel(const unsigned short* __restrict__ h, const unsigned short* __restrict__ wdT,
                  float* __restrict__ y) {
  __shared__ unsigned short lds[2 * 256 * 64 + 2 * 128 * 64];
  int flat = blockIdx.x;                 // 640 blocks
  int e = flat & 7, idx = flat >> 3;     // [0,80): chunks of 16 (8bx x 2by)
  int c = idx >> 4, i = idx & 15;
  int bx = i & 7, by = c * 2 + (i >> 3);
  const unsigned short* Ag = h   + ((size_t)e * CAP  + (size_t)by * 256) * FDIM;
  const unsigned short* Bg = wdT + ((size_t)e * HDIM + (size_t)bx * 128) * FDIM;
  f32x4 acc[4][4];
#pragma unroll
  for (int m = 0; m < 4; ++m)
#pragma unroll
    for (int n = 0; n < 4; ++n) acc[m][n] = (f32x4){0.f, 0.f, 0.f, 0.f};
  mainloop8<128>(Ag, Bg, FDIM, FDIM, FDIM / 64, lds, acc);

  int lane = threadIdx.x & 63, wid = threadIdx.x >> 6;
  int qr = wid >> 1, qc = wid & 1, fr = lane & 15, fg = lane >> 4;
  size_t rbase = (size_t)e * CAP + by * 256;
#pragma unroll
  for (int mi = 0; mi < 4; ++mi) {
    int row0 = (mi >> 1) * 128 + qr * 32 + (mi & 1) * 16 + fg * 4;
#pragma unroll
    for (int ni = 0; ni < 4; ++ni) {
      int col = bx * 128 + (ni >> 1) * 64 + qc * 32 + (ni & 1) * 16 + fr;
#pragma unroll
      for (int v = 0; v < 4; ++v)
        y[(rbase + row0 + v) * HDIM + col] = acc[mi][ni][v];
    }
  }
}

// ---------------- combine: out[t] = sum_k w_k * y[e_k, slot_k]
__global__ __launch_bounds__(256)
void combine_kernel(const float* __restrict__ y, const int* __restrict__ topsel,
                    const int* __restrict__ slot, const float* __restrict__ wts,
                    float* __restrict__ out) {
  int t = blockIdx.x;
  int i = threadIdx.x * 4;
  float4 s = {0.f, 0.f, 0.f, 0.f};
#pragma unroll
  for (int k = 0; k < 2; ++k) {
    int sl = slot[t * 2 + k];
    if (sl >= 0) {
      int e = topsel[t * 2 + k];
      float w = wts[t * 2 + k];
      float4 v = *(const float4*)(y + ((size_t)e * CAP + sl) * HDIM + i);
      s.x += w * v.x; s.y += w * v.y; s.z += w * v.z; s.w += w * v.w;
    }
  }
  *(float4*)(out + (size_t)t * HDIM + i) = s;
}

extern "C" void kernel_launch(void* const* d_in, const int* in_sizes, int n_in,
                              void* d_out, int out_size, void* d_ws, size_t ws_size,
                              hipStream_t stream) {
  const float* tokens   = (const float*)d_in[0];
  const float* w_router = (const float*)d_in[1];
  const float* w_gate   = (const float*)d_in[2];
  const float* w_up     = (const float*)d_in[3];
  const float* w_down   = (const float*)d_in[4];
  float* out = (float*)d_out;
  char* ws = (char*)d_ws;

  const size_t WGU = (size_t)NE * 2 * FDIM * HDIM * 2;  // 128 MiB interleaved gate/up bf16
  const size_t WD  = (size_t)NE * HDIM * FDIM * 2;      // 64 MiB
  const size_t XB  = (size_t)NE * CAP * HDIM * 2;       // 40 MiB
  const size_t HB  = (size_t)NE * CAP * FDIM * 2;       // 160 MiB
  unsigned short* wguT = (unsigned short*)(ws);
  unsigned short* wdT  = (unsigned short*)(ws + WGU);
  unsigned short* xbuf = (unsigned short*)(ws + WGU + WD);
  unsigned short* hbuf = (unsigned short*)(ws + WGU + WD + XB);
  float* ybuf = (float*)(ws);                           // aliases wguT (dead after gemm1)
  char* tail = ws + WGU + WD + XB + HB;
  int*   topsel  = (int*)tail;
  float* wtsv    = (float*)(tail + (size_t)T_TOK * 2 * 4);
  int*   slotv   = (int*)(tail + (size_t)T_TOK * 2 * 8);
  int*   src_tok = (int*)(tail + (size_t)T_TOK * 2 * 12);

  hipMemsetAsync(src_tok, 0xFF, (size_t)NE * CAP * 4, stream);

  transpose_cvt_gu<<<dim3(FDIM / 64, HDIM / 64, NE), 256, 0, stream>>>(w_gate, wguT, 0);
  transpose_cvt_gu<<<dim3(FDIM / 64, HDIM / 64, NE), 256, 0, stream>>>(w_up,   wguT, 1);
  transpose_cvt<<<dim3(HDIM / 64, FDIM / 64, NE), 256, 0, stream>>>(w_down, wdT, FDIM, HDIM);

  router_kernel<<<T_TOK / 4, 256, 0, stream>>>(tokens, w_router, topsel, wtsv);
  dispatch_kernel<<<NE, 256, 0, stream>>>(topsel, slotv, src_tok);
  gather_x<<<NE * CAP, 128, 0, stream>>>(tokens, src_tok, xbuf);

  gemm1_kernel<<<2560, 512, 0, stream>>>(xbuf, wguT, hbuf);
  gemm2_kernel<<<640, 512, 0, stream>>>(hbuf, wdT, ybuf);

  combine_kernel<<<T_TOK, 256, 0, stream>>>(ybuf, topsel, slotv, wtsv, out);
}